// Round 11
// baseline (119.981 us; speedup 1.0000x reference)
//
#include <hip/hip_runtime.h>
#include <math.h>

namespace {
constexpr int kB = 256;
constexpr int kN = 1024;
constexpr int kC = 512;
constexpr int kNP1 = kN + 1;  // 1025 (visual rows + dustbin)
constexpr float kEPS = 1e-6f;
constexpr float kPOW = 0.9523809523809523f;    // ALPHA/(ALPHA+REG) = 1/1.05
constexpr float kSCALE = 28.8539008177792681f; // 20 * log2(e)

// series constants: gamma = u*K*(u*K+eps)^-POW, K = 2^-30 * Ks
//   p_obs = u*2^-30*eps^-POW * [M1 - POW*z*M2 + c2*z^2*M3 - c3*z^3*M4],
//   z = u * 2^-30/eps,  M_j = sum_n Ks_n^j * vis_nc
constexpr float kBaseC = 4.823755e-4f;   // 2^-30 * eps^-POW
constexpr float kZC = 9.3132257e-4f;     // 2^-30 / eps
constexpr float kC2 = 0.92970522f;       // POW(POW+1)/2
constexpr float kC3 = 0.91494840f;       // POW(POW+1)(POW+2)/6

constexpr int kChunksPerB = 8;           // blocks per batch (was 4)
constexpr int kBlocks = kB * kChunksPerB;  // 2048

// ---- fast-path ws layout (bytes) ----
// sim      : [0, kB*kNP1*4)                       1,049,600 B
// partials : [+kBlocks * 4 moments * 512c * 4B)  16,777,216 B
constexpr size_t kSimBytes = (size_t)kB * kNP1 * sizeof(float);
constexpr size_t kPartOffB = kSimBytes;
constexpr size_t kWsNeeded =
    kSimBytes + (size_t)kBlocks * 4 * kC * sizeof(float);

// ---- fallback ws layout (floats) ----
constexpr size_t kFbSimOff = 0;
constexpr size_t kFbGammaOff = (size_t)kB * kNP1;
constexpr size_t kFbPartialOff = kFbGammaOff + (size_t)kB * kN;
constexpr int kNSplit = 4;
constexpr int kRowsPerSplit = kN / kNSplit;  // 256

typedef float f32x4 __attribute__((ext_vector_type(4)));
}  // namespace

// ===========================================================================
// K1: sims + 4 K-weighted moment partials, single pass over vis.
// 2048 blocks (8 per batch) x 256 threads (4 waves); wave owns 32 rows;
// lane owns channels [lane*8, lane*8+8). Moments accumulate in registers.
// ===========================================================================
__global__ __launch_bounds__(256) void sim_moment_kernel(
    const float* __restrict__ prompt,    // [B, C]
    const float* __restrict__ vis,       // [B, N, C]
    const float* __restrict__ dustbin,   // [C]
    float* __restrict__ sim,             // [B, NP1] (ws)
    float* __restrict__ partials) {      // [kBlocks][4][512] (ws)
  const int w = threadIdx.x >> 6;        // wave 0..3
  const int lane = threadIdx.x & 63;
  const int b = blockIdx.x >> 3;
  const int chunk = blockIdx.x & 7;
  const int coff = lane * 8;

  __shared__ float lds[4][4][kC];  // 32 KB [wave][moment][channel]

  // prompt fragment + norm (once per wave)
  const float* prow = prompt + (size_t)b * kC;
  const f32x4 pa = *reinterpret_cast<const f32x4*>(prow + coff);
  const f32x4 pb = *reinterpret_cast<const f32x4*>(prow + coff + 4);
  float psq = pa.x * pa.x + pa.y * pa.y + pa.z * pa.z + pa.w * pa.w +
              pb.x * pb.x + pb.y * pb.y + pb.z * pb.z + pb.w * pb.w;
#pragma unroll
  for (int s = 1; s < 64; s <<= 1) psq += __shfl_xor(psq, s);
  const float pn = fmaxf(sqrtf(psq), 1e-12f);

  const int n0 = chunk * 128 + w * 32;   // first row of this wave
  const float* vbase = vis + ((size_t)b * kN + n0) * kC;
  float* simw = sim + (size_t)b * kNP1 + n0;

  float m1[8] = {0, 0, 0, 0, 0, 0, 0, 0};
  float m2[8] = {0, 0, 0, 0, 0, 0, 0, 0};
  float m3[8] = {0, 0, 0, 0, 0, 0, 0, 0};
  float m4[8] = {0, 0, 0, 0, 0, 0, 0, 0};

#pragma unroll 4
  for (int r = 0; r < 32; ++r) {
    const float* vrow = vbase + (size_t)r * kC;
    const f32x4 va = __builtin_nontemporal_load(
        reinterpret_cast<const f32x4*>(vrow + coff));
    const f32x4 vb = __builtin_nontemporal_load(
        reinterpret_cast<const f32x4*>(vrow + coff + 4));

    float dot = va.x * pa.x + va.y * pa.y + va.z * pa.z + va.w * pa.w +
                vb.x * pb.x + vb.y * pb.y + vb.z * pb.z + vb.w * pb.w;
    float vsq = va.x * va.x + va.y * va.y + va.z * va.z + va.w * va.w +
                vb.x * vb.x + vb.y * vb.y + vb.z * vb.z + vb.w * vb.w;
#pragma unroll
    for (int s = 1; s < 64; s <<= 1) {
      dot += __shfl_xor(dot, s);
      vsq += __shfl_xor(vsq, s);
    }
    const float sm = dot / (pn * fmaxf(sqrtf(vsq), 1e-12f));
    if (lane == 0) simw[r] = sm;

    // Ks = 2^30 * K = exp2(SCALE*(sim-1) + 30); range ~[0.03, 150]
    const float Ks = exp2f(kSCALE * (sm - 1.0f) + 30.0f);
    const float Ks2 = Ks * Ks;
    const float Ks3 = Ks2 * Ks;
    const float Ks4 = Ks2 * Ks2;
    m1[0] += Ks * va.x; m1[1] += Ks * va.y; m1[2] += Ks * va.z; m1[3] += Ks * va.w;
    m1[4] += Ks * vb.x; m1[5] += Ks * vb.y; m1[6] += Ks * vb.z; m1[7] += Ks * vb.w;
    m2[0] += Ks2 * va.x; m2[1] += Ks2 * va.y; m2[2] += Ks2 * va.z; m2[3] += Ks2 * va.w;
    m2[4] += Ks2 * vb.x; m2[5] += Ks2 * vb.y; m2[6] += Ks2 * vb.z; m2[7] += Ks2 * vb.w;
    m3[0] += Ks3 * va.x; m3[1] += Ks3 * va.y; m3[2] += Ks3 * va.z; m3[3] += Ks3 * va.w;
    m3[4] += Ks3 * vb.x; m3[5] += Ks3 * vb.y; m3[6] += Ks3 * vb.z; m3[7] += Ks3 * vb.w;
    m4[0] += Ks4 * va.x; m4[1] += Ks4 * va.y; m4[2] += Ks4 * va.z; m4[3] += Ks4 * va.w;
    m4[4] += Ks4 * vb.x; m4[5] += Ks4 * vb.y; m4[6] += Ks4 * vb.z; m4[7] += Ks4 * vb.w;
  }

  // dustbin sim (one wave per batch; excluded from moments/outputs)
  if (chunk == 7 && w == 3) {
    const f32x4 da = *reinterpret_cast<const f32x4*>(dustbin + coff);
    const f32x4 db = *reinterpret_cast<const f32x4*>(dustbin + coff + 4);
    float dot = da.x * pa.x + da.y * pa.y + da.z * pa.z + da.w * pa.w +
                db.x * pb.x + db.y * pb.y + db.z * pb.z + db.w * pb.w;
    float vsq = da.x * da.x + da.y * da.y + da.z * da.z + da.w * da.w +
                db.x * db.x + db.y * db.y + db.z * db.z + db.w * db.w;
#pragma unroll
    for (int s = 1; s < 64; s <<= 1) {
      dot += __shfl_xor(dot, s);
      vsq += __shfl_xor(vsq, s);
    }
    if (lane == 0)
      sim[(size_t)b * kNP1 + kN] = dot / (pn * fmaxf(sqrtf(vsq), 1e-12f));
  }

  // block-level moment reduce via LDS
#pragma unroll
  for (int j = 0; j < 8; ++j) {
    lds[w][0][coff + j] = m1[j];
    lds[w][1][coff + j] = m2[j];
    lds[w][2][coff + j] = m3[j];
    lds[w][3][coff + j] = m4[j];
  }
  __syncthreads();
#pragma unroll
  for (int h = 0; h < 2; ++h) {
    const int c = (int)threadIdx.x + h * 256;
#pragma unroll
    for (int m = 0; m < 4; ++m) {
      const float s =
          lds[0][m][c] + lds[1][m][c] + lds[2][m][c] + lds[3][m][c];
      partials[((size_t)blockIdx.x * 4 + m) * kC + c] = s;
    }
  }
}

// ===========================================================================
// K2': exact Sinkhorn from sims (unchanged math) -> u; exact total_mass;
// p_obs from the 4-moment series. One 1024-thread block per batch.
// ===========================================================================
__global__ __launch_bounds__(1024) void sinkhorn_combine_kernel(
    const float* __restrict__ sim,        // [B, NP1]
    const float* __restrict__ partials,   // [kBlocks][4][512]
    float* __restrict__ p_obs,            // [B, C]
    float* __restrict__ mass_out) {       // [B]
  const int b = blockIdx.x;
  const int t = threadIdx.x;
  __shared__ float red[16];

  const float* simb = sim + (size_t)b * kNP1;
  const float K0 = exp2f((simb[t] - 1.0f) * kSCALE);
  const float Kd = (t == 0) ? exp2f((simb[kN] - 1.0f) * kSCALE) : 0.0f;
  float v0 = 1.0f, vd = 1.0f, u = 1.0f;

#pragma unroll
  for (int it = 0; it < 3; ++it) {
    float partial = K0 * v0 + Kd * vd;
#pragma unroll
    for (int s = 1; s < 64; s <<= 1) partial += __shfl_xor(partial, s);
    if ((t & 63) == 0) red[t >> 6] = partial;
    __syncthreads();
    float Kv = 0.f;
#pragma unroll
    for (int w = 0; w < 16; ++w) Kv += red[w];
    __syncthreads();
    u = exp2f(-kPOW * log2f(Kv + kEPS));
    v0 = exp2f(-kPOW * log2f(u * K0 + kEPS));
    vd = exp2f(-kPOW * log2f(u * Kd + kEPS));
  }

  // exact gamma for n = t (< N always) -> total_mass
  const float g = u * K0 * v0;
  float pm = g;
#pragma unroll
  for (int s = 1; s < 64; s <<= 1) pm += __shfl_xor(pm, s);
  if ((t & 63) == 0) red[t >> 6] = pm;
  __syncthreads();
  if (t == 0) {
    float m = 0.f;
#pragma unroll
    for (int w = 0; w < 16; ++w) m += red[w];
    mass_out[b] = m;
  }

  // p_obs via moment series
  if (t < kC) {
    float M1 = 0.f, M2 = 0.f, M3 = 0.f, M4 = 0.f;
#pragma unroll
    for (int k = 0; k < kChunksPerB; ++k) {
      const size_t blk = (size_t)(b * kChunksPerB + k);
      M1 += partials[(blk * 4 + 0) * kC + t];
      M2 += partials[(blk * 4 + 1) * kC + t];
      M3 += partials[(blk * 4 + 2) * kC + t];
      M4 += partials[(blk * 4 + 3) * kC + t];
    }
    const float z = u * kZC;
    const float base = u * kBaseC;
    const float p =
        base * (M1 + z * (-kPOW * M2 + z * (kC2 * M3 - z * (kC3 * M4))));
    p_obs[(size_t)b * kC + t] = p;
  }
}

// ===========================================================================
// FALLBACK (fp32 two-pass, round-1 proven; used only if ws too small)
// ===========================================================================
__global__ __launch_bounds__(256) void sim_kernel(
    const float* __restrict__ prompt, const float* __restrict__ vis,
    const float* __restrict__ dustbin, float* __restrict__ sim) {
  const int wid = threadIdx.x >> 6;
  const int lane = threadIdx.x & 63;
  const long long row = (long long)blockIdx.x * 4 + wid;
  if (row >= (long long)kB * kNP1) return;
  const int b = (int)(row / kNP1);
  const int n = (int)(row % kNP1);
  const float* vrow = (n < kN) ? (vis + ((size_t)b * kN + n) * kC) : dustbin;
  const float* prow = prompt + (size_t)b * kC;
  float dot = 0.f, vsq = 0.f, psq = 0.f;
#pragma unroll
  for (int h = 0; h < 2; ++h) {
    const int off = h * 256 + lane * 4;
    const float4 v4 = *reinterpret_cast<const float4*>(vrow + off);
    const float4 p4 = *reinterpret_cast<const float4*>(prow + off);
    dot += v4.x * p4.x + v4.y * p4.y + v4.z * p4.z + v4.w * p4.w;
    vsq += v4.x * v4.x + v4.y * v4.y + v4.z * v4.z + v4.w * v4.w;
    psq += p4.x * p4.x + p4.y * p4.y + p4.z * p4.z + p4.w * p4.w;
  }
#pragma unroll
  for (int s = 1; s < 64; s <<= 1) {
    dot += __shfl_xor(dot, s);
    vsq += __shfl_xor(vsq, s);
    psq += __shfl_xor(psq, s);
  }
  if (lane == 0) {
    const float pn = fmaxf(sqrtf(psq), 1e-12f);
    const float vn = fmaxf(sqrtf(vsq), 1e-12f);
    sim[row] = dot / (pn * vn);
  }
}

__global__ __launch_bounds__(1024) void sinkhorn_kernel(
    const float* __restrict__ sim, float* __restrict__ gamma,
    float* __restrict__ mass_out) {
  const int b = blockIdx.x;
  const int t = threadIdx.x;
  __shared__ float red[16];
  const float* simb = sim + (size_t)b * kNP1;
  const float K0 = exp2f((simb[t] - 1.0f) * kSCALE);
  const float K1 = (t == 0) ? exp2f((simb[kN] - 1.0f) * kSCALE) : 0.0f;
  float v0 = 1.0f, v1 = 1.0f, u = 1.0f;
  for (int it = 0; it < 3; ++it) {
    float partial = K0 * v0 + K1 * v1;
#pragma unroll
    for (int s = 1; s < 64; s <<= 1) partial += __shfl_xor(partial, s);
    if ((t & 63) == 0) red[t >> 6] = partial;
    __syncthreads();
    float Kv = 0.f;
#pragma unroll
    for (int w = 0; w < 16; ++w) Kv += red[w];
    __syncthreads();
    u = exp2f(-kPOW * log2f(Kv + kEPS));
    v0 = exp2f(-kPOW * log2f(u * K0 + kEPS));
    v1 = exp2f(-kPOW * log2f(u * K1 + kEPS));
  }
  const float g0 = u * K0 * v0;
  gamma[(size_t)b * kN + t] = g0;
  float partial = g0;
#pragma unroll
  for (int s = 1; s < 64; s <<= 1) partial += __shfl_xor(partial, s);
  if ((t & 63) == 0) red[t >> 6] = partial;
  __syncthreads();
  if (t == 0) {
    float m = 0.f;
#pragma unroll
    for (int w = 0; w < 16; ++w) m += red[w];
    mass_out[b] = m;
  }
}

__global__ __launch_bounds__(512) void pobs_kernel(
    const float* __restrict__ vis, const float* __restrict__ gamma,
    float* __restrict__ partial) {
  const int b = blockIdx.x / kNSplit;
  const int s = blockIdx.x % kNSplit;
  const int c = threadIdx.x;
  __shared__ float gsm[kRowsPerSplit];
  const float* g = gamma + (size_t)b * kN + (size_t)s * kRowsPerSplit;
  for (int i = threadIdx.x; i < kRowsPerSplit; i += 512) gsm[i] = g[i];
  __syncthreads();
  const float* vbase = vis + ((size_t)b * kN + (size_t)s * kRowsPerSplit) * kC;
  float acc = 0.f;
#pragma unroll 8
  for (int n = 0; n < kRowsPerSplit; ++n)
    acc += gsm[n] * vbase[(size_t)n * kC + c];
  partial[(size_t)blockIdx.x * kC + c] = acc;
}

__global__ __launch_bounds__(256) void reduce_kernel(
    const float* __restrict__ partial, float* __restrict__ p_obs) {
  const int i = blockIdx.x * 256 + threadIdx.x;
  if (i >= kB * kC) return;
  const int b = i / kC;
  const int c = i % kC;
  float s = 0.f;
#pragma unroll
  for (int k = 0; k < kNSplit; ++k)
    s += partial[((size_t)(b * kNSplit + k)) * kC + c];
  p_obs[i] = s;
}

// ===========================================================================

extern "C" void kernel_launch(void* const* d_in, const int* in_sizes, int n_in,
                              void* d_out, int out_size, void* d_ws,
                              size_t ws_size, hipStream_t stream) {
  const float* prompt = (const float*)d_in[0];
  const float* vis = (const float*)d_in[1];
  const float* dustbin = (const float*)d_in[2];
  float* out = (float*)d_out;  // p_obs [B*C] then total_mass [B]

  if (ws_size >= kWsNeeded) {
    float* sim = (float*)d_ws;
    float* partials = (float*)((unsigned char*)d_ws + kPartOffB);
    sim_moment_kernel<<<kBlocks, 256, 0, stream>>>(prompt, vis, dustbin, sim,
                                                   partials);
    sinkhorn_combine_kernel<<<kB, 1024, 0, stream>>>(
        sim, partials, out, out + (size_t)kB * kC);
  } else {
    float* ws = (float*)d_ws;
    float* sim = ws + kFbSimOff;
    float* gamma = ws + kFbGammaOff;
    float* partial = ws + kFbPartialOff;
    const long long rows = (long long)kB * kNP1;
    sim_kernel<<<(int)((rows + 3) / 4), 256, 0, stream>>>(prompt, vis,
                                                          dustbin, sim);
    sinkhorn_kernel<<<kB, 1024, 0, stream>>>(sim, gamma, out + (size_t)kB * kC);
    pobs_kernel<<<kB * kNSplit, 512, 0, stream>>>(vis, gamma, partial);
    reduce_kernel<<<(kB * kC + 255) / 256, 256, 0, stream>>>(partial, out);
  }
}

// Round 12
// 113.779 us; speedup vs baseline: 1.0545x; 1.0545x over previous
//
#include <hip/hip_runtime.h>
#include <math.h>

namespace {
constexpr int kB = 256;
constexpr int kN = 1024;
constexpr int kC = 512;
constexpr int kNP1 = kN + 1;  // 1025 (visual rows + dustbin)
constexpr float kEPS = 1e-6f;
constexpr float kPOW = 0.9523809523809523f;    // ALPHA/(ALPHA+REG) = 1/1.05
constexpr float kSCALE = 28.8539008177792681f; // 20 * log2(e)

// series constants: gamma = u*K*(u*K+eps)^-POW, K = 2^-30 * Ks
//   p_obs = u*2^-30*eps^-POW * [M1 - POW*z*M2 + c2*z^2*M3 - c3*z^3*M4],
//   z = u * 2^-30/eps,  M_j = sum_n Ks_n^j * vis_nc
constexpr float kBaseC = 4.823755e-4f;   // 2^-30 * eps^-POW
constexpr float kZC = 9.3132257e-4f;     // 2^-30 / eps
constexpr float kC2 = 0.92970522f;       // POW(POW+1)/2
constexpr float kC3 = 0.91494840f;       // POW(POW+1)(POW+2)/6

constexpr int kChunksPerB = 4;             // round-10 geometry (proven)
constexpr int kBlocks = kB * kChunksPerB;  // 1024

// ---- fast-path ws layout (bytes) ----
// sim      : [0, kB*kNP1*4)                      1,049,600 B
// partials : [+kBlocks * 4 moments * 512c * 4B)  8,388,608 B
constexpr size_t kSimBytes = (size_t)kB * kNP1 * sizeof(float);
constexpr size_t kPartOffB = kSimBytes;
constexpr size_t kWsNeeded =
    kSimBytes + (size_t)kBlocks * 4 * kC * sizeof(float);

// ---- fallback ws layout (floats) ----
constexpr size_t kFbSimOff = 0;
constexpr size_t kFbGammaOff = (size_t)kB * kNP1;
constexpr size_t kFbPartialOff = kFbGammaOff + (size_t)kB * kN;
constexpr int kNSplit = 4;
constexpr int kRowsPerSplit = kN / kNSplit;  // 256

typedef float f32x4 __attribute__((ext_vector_type(4)));
}  // namespace

// ===========================================================================
// K1: sims + 4 K-weighted moment partials, single pass over vis.
// 1024 blocks (4 per batch) x 256 threads (4 waves); wave owns 64 rows,
// processed TWO AT A TIME so the two shuffle-reduce chains interleave and
// the DS-latency stall is paid once per 4 KB instead of once per 2 KB.
// ===========================================================================
__global__ __launch_bounds__(256) void sim_moment_kernel(
    const float* __restrict__ prompt,    // [B, C]
    const float* __restrict__ vis,       // [B, N, C]
    const float* __restrict__ dustbin,   // [C]
    float* __restrict__ sim,             // [B, NP1] (ws)
    float* __restrict__ partials) {      // [kBlocks][4][512] (ws)
  const int w = threadIdx.x >> 6;        // wave 0..3
  const int lane = threadIdx.x & 63;
  const int b = blockIdx.x >> 2;
  const int chunk = blockIdx.x & 3;
  const int coff = lane * 8;

  __shared__ float lds[4][4][kC];  // 32 KB [wave][moment][channel]

  // prompt fragment + norm (once per wave)
  const float* prow = prompt + (size_t)b * kC;
  const f32x4 pa = *reinterpret_cast<const f32x4*>(prow + coff);
  const f32x4 pb = *reinterpret_cast<const f32x4*>(prow + coff + 4);
  float psq = pa.x * pa.x + pa.y * pa.y + pa.z * pa.z + pa.w * pa.w +
              pb.x * pb.x + pb.y * pb.y + pb.z * pb.z + pb.w * pb.w;
#pragma unroll
  for (int s = 1; s < 64; s <<= 1) psq += __shfl_xor(psq, s);
  const float pn = fmaxf(sqrtf(psq), 1e-12f);

  const int n0 = chunk * 256 + w * 64;   // first row of this wave
  const float* vbase = vis + ((size_t)b * kN + n0) * kC;
  float* simw = sim + (size_t)b * kNP1 + n0;

  float m1[8] = {0, 0, 0, 0, 0, 0, 0, 0};
  float m2[8] = {0, 0, 0, 0, 0, 0, 0, 0};
  float m3[8] = {0, 0, 0, 0, 0, 0, 0, 0};
  float m4[8] = {0, 0, 0, 0, 0, 0, 0, 0};

#pragma unroll 2
  for (int rr = 0; rr < 32; ++rr) {
    const float* vrow0 = vbase + (size_t)(2 * rr) * kC;
    const float* vrow1 = vbase + (size_t)(2 * rr + 1) * kC;
    const f32x4 va0 = __builtin_nontemporal_load(
        reinterpret_cast<const f32x4*>(vrow0 + coff));
    const f32x4 vb0 = __builtin_nontemporal_load(
        reinterpret_cast<const f32x4*>(vrow0 + coff + 4));
    const f32x4 va1 = __builtin_nontemporal_load(
        reinterpret_cast<const f32x4*>(vrow1 + coff));
    const f32x4 vb1 = __builtin_nontemporal_load(
        reinterpret_cast<const f32x4*>(vrow1 + coff + 4));

    float dot0 = va0.x * pa.x + va0.y * pa.y + va0.z * pa.z + va0.w * pa.w +
                 vb0.x * pb.x + vb0.y * pb.y + vb0.z * pb.z + vb0.w * pb.w;
    float vsq0 = va0.x * va0.x + va0.y * va0.y + va0.z * va0.z + va0.w * va0.w +
                 vb0.x * vb0.x + vb0.y * vb0.y + vb0.z * vb0.z + vb0.w * vb0.w;
    float dot1 = va1.x * pa.x + va1.y * pa.y + va1.z * pa.z + va1.w * pa.w +
                 vb1.x * pb.x + vb1.y * pb.y + vb1.z * pb.z + vb1.w * pb.w;
    float vsq1 = va1.x * va1.x + va1.y * va1.y + va1.z * va1.z + va1.w * va1.w +
                 vb1.x * vb1.x + vb1.y * vb1.y + vb1.z * vb1.z + vb1.w * vb1.w;

    // four interleaved butterfly chains
#pragma unroll
    for (int s = 1; s < 64; s <<= 1) {
      dot0 += __shfl_xor(dot0, s);
      vsq0 += __shfl_xor(vsq0, s);
      dot1 += __shfl_xor(dot1, s);
      vsq1 += __shfl_xor(vsq1, s);
    }
    const float sm0 = dot0 / (pn * fmaxf(sqrtf(vsq0), 1e-12f));
    const float sm1 = dot1 / (pn * fmaxf(sqrtf(vsq1), 1e-12f));
    if (lane == 0) {
      simw[2 * rr] = sm0;
      simw[2 * rr + 1] = sm1;
    }

    // Ks = 2^30 * K = exp2(SCALE*(sim-1) + 30); range ~[0.03, 150]
    const float Ks0 = exp2f(kSCALE * (sm0 - 1.0f) + 30.0f);
    const float Ks1 = exp2f(kSCALE * (sm1 - 1.0f) + 30.0f);
    const float Ks0_2 = Ks0 * Ks0, Ks1_2 = Ks1 * Ks1;
    const float Ks0_3 = Ks0_2 * Ks0, Ks1_3 = Ks1_2 * Ks1;
    const float Ks0_4 = Ks0_2 * Ks0_2, Ks1_4 = Ks1_2 * Ks1_2;

    m1[0] += Ks0 * va0.x + Ks1 * va1.x;  m1[1] += Ks0 * va0.y + Ks1 * va1.y;
    m1[2] += Ks0 * va0.z + Ks1 * va1.z;  m1[3] += Ks0 * va0.w + Ks1 * va1.w;
    m1[4] += Ks0 * vb0.x + Ks1 * vb1.x;  m1[5] += Ks0 * vb0.y + Ks1 * vb1.y;
    m1[6] += Ks0 * vb0.z + Ks1 * vb1.z;  m1[7] += Ks0 * vb0.w + Ks1 * vb1.w;
    m2[0] += Ks0_2 * va0.x + Ks1_2 * va1.x;  m2[1] += Ks0_2 * va0.y + Ks1_2 * va1.y;
    m2[2] += Ks0_2 * va0.z + Ks1_2 * va1.z;  m2[3] += Ks0_2 * va0.w + Ks1_2 * va1.w;
    m2[4] += Ks0_2 * vb0.x + Ks1_2 * vb1.x;  m2[5] += Ks0_2 * vb0.y + Ks1_2 * vb1.y;
    m2[6] += Ks0_2 * vb0.z + Ks1_2 * vb1.z;  m2[7] += Ks0_2 * vb0.w + Ks1_2 * vb1.w;
    m3[0] += Ks0_3 * va0.x + Ks1_3 * va1.x;  m3[1] += Ks0_3 * va0.y + Ks1_3 * va1.y;
    m3[2] += Ks0_3 * va0.z + Ks1_3 * va1.z;  m3[3] += Ks0_3 * va0.w + Ks1_3 * va1.w;
    m3[4] += Ks0_3 * vb0.x + Ks1_3 * vb1.x;  m3[5] += Ks0_3 * vb0.y + Ks1_3 * vb1.y;
    m3[6] += Ks0_3 * vb0.z + Ks1_3 * vb1.z;  m3[7] += Ks0_3 * vb0.w + Ks1_3 * vb1.w;
    m4[0] += Ks0_4 * va0.x + Ks1_4 * va1.x;  m4[1] += Ks0_4 * va0.y + Ks1_4 * va1.y;
    m4[2] += Ks0_4 * va0.z + Ks1_4 * va1.z;  m4[3] += Ks0_4 * va0.w + Ks1_4 * va1.w;
    m4[4] += Ks0_4 * vb0.x + Ks1_4 * vb1.x;  m4[5] += Ks0_4 * vb0.y + Ks1_4 * vb1.y;
    m4[6] += Ks0_4 * vb0.z + Ks1_4 * vb1.z;  m4[7] += Ks0_4 * vb0.w + Ks1_4 * vb1.w;
  }

  // dustbin sim (one wave per batch; excluded from moments/outputs)
  if (chunk == 3 && w == 3) {
    const f32x4 da = *reinterpret_cast<const f32x4*>(dustbin + coff);
    const f32x4 db = *reinterpret_cast<const f32x4*>(dustbin + coff + 4);
    float dot = da.x * pa.x + da.y * pa.y + da.z * pa.z + da.w * pa.w +
                db.x * pb.x + db.y * pb.y + db.z * pb.z + db.w * pb.w;
    float vsq = da.x * da.x + da.y * da.y + da.z * da.z + da.w * da.w +
                db.x * db.x + db.y * db.y + db.z * db.z + db.w * db.w;
#pragma unroll
    for (int s = 1; s < 64; s <<= 1) {
      dot += __shfl_xor(dot, s);
      vsq += __shfl_xor(vsq, s);
    }
    if (lane == 0)
      sim[(size_t)b * kNP1 + kN] = dot / (pn * fmaxf(sqrtf(vsq), 1e-12f));
  }

  // block-level moment reduce via LDS
#pragma unroll
  for (int j = 0; j < 8; ++j) {
    lds[w][0][coff + j] = m1[j];
    lds[w][1][coff + j] = m2[j];
    lds[w][2][coff + j] = m3[j];
    lds[w][3][coff + j] = m4[j];
  }
  __syncthreads();
#pragma unroll
  for (int h = 0; h < 2; ++h) {
    const int c = (int)threadIdx.x + h * 256;
#pragma unroll
    for (int m = 0; m < 4; ++m) {
      const float s =
          lds[0][m][c] + lds[1][m][c] + lds[2][m][c] + lds[3][m][c];
      partials[((size_t)blockIdx.x * 4 + m) * kC + c] = s;
    }
  }
}

// ===========================================================================
// K2': exact Sinkhorn from sims (unchanged math) -> u; exact total_mass;
// p_obs from the 4-moment series. One 1024-thread block per batch.
// ===========================================================================
__global__ __launch_bounds__(1024) void sinkhorn_combine_kernel(
    const float* __restrict__ sim,        // [B, NP1]
    const float* __restrict__ partials,   // [kBlocks][4][512]
    float* __restrict__ p_obs,            // [B, C]
    float* __restrict__ mass_out) {       // [B]
  const int b = blockIdx.x;
  const int t = threadIdx.x;
  __shared__ float red[16];

  const float* simb = sim + (size_t)b * kNP1;
  const float K0 = exp2f((simb[t] - 1.0f) * kSCALE);
  const float Kd = (t == 0) ? exp2f((simb[kN] - 1.0f) * kSCALE) : 0.0f;
  float v0 = 1.0f, vd = 1.0f, u = 1.0f;

#pragma unroll
  for (int it = 0; it < 3; ++it) {
    float partial = K0 * v0 + Kd * vd;
#pragma unroll
    for (int s = 1; s < 64; s <<= 1) partial += __shfl_xor(partial, s);
    if ((t & 63) == 0) red[t >> 6] = partial;
    __syncthreads();
    float Kv = 0.f;
#pragma unroll
    for (int w = 0; w < 16; ++w) Kv += red[w];
    __syncthreads();
    u = exp2f(-kPOW * log2f(Kv + kEPS));
    v0 = exp2f(-kPOW * log2f(u * K0 + kEPS));
    vd = exp2f(-kPOW * log2f(u * Kd + kEPS));
  }

  // exact gamma for n = t (< N always) -> total_mass
  const float g = u * K0 * v0;
  float pm = g;
#pragma unroll
  for (int s = 1; s < 64; s <<= 1) pm += __shfl_xor(pm, s);
  if ((t & 63) == 0) red[t >> 6] = pm;
  __syncthreads();
  if (t == 0) {
    float m = 0.f;
#pragma unroll
    for (int w = 0; w < 16; ++w) m += red[w];
    mass_out[b] = m;
  }

  // p_obs via moment series
  if (t < kC) {
    float M1 = 0.f, M2 = 0.f, M3 = 0.f, M4 = 0.f;
#pragma unroll
    for (int k = 0; k < kChunksPerB; ++k) {
      const size_t blk = (size_t)(b * kChunksPerB + k);
      M1 += partials[(blk * 4 + 0) * kC + t];
      M2 += partials[(blk * 4 + 1) * kC + t];
      M3 += partials[(blk * 4 + 2) * kC + t];
      M4 += partials[(blk * 4 + 3) * kC + t];
    }
    const float z = u * kZC;
    const float base = u * kBaseC;
    const float p =
        base * (M1 + z * (-kPOW * M2 + z * (kC2 * M3 - z * (kC3 * M4))));
    p_obs[(size_t)b * kC + t] = p;
  }
}

// ===========================================================================
// FALLBACK (fp32 two-pass, round-1 proven; used only if ws too small)
// ===========================================================================
__global__ __launch_bounds__(256) void sim_kernel(
    const float* __restrict__ prompt, const float* __restrict__ vis,
    const float* __restrict__ dustbin, float* __restrict__ sim) {
  const int wid = threadIdx.x >> 6;
  const int lane = threadIdx.x & 63;
  const long long row = (long long)blockIdx.x * 4 + wid;
  if (row >= (long long)kB * kNP1) return;
  const int b = (int)(row / kNP1);
  const int n = (int)(row % kNP1);
  const float* vrow = (n < kN) ? (vis + ((size_t)b * kN + n) * kC) : dustbin;
  const float* prow = prompt + (size_t)b * kC;
  float dot = 0.f, vsq = 0.f, psq = 0.f;
#pragma unroll
  for (int h = 0; h < 2; ++h) {
    const int off = h * 256 + lane * 4;
    const float4 v4 = *reinterpret_cast<const float4*>(vrow + off);
    const float4 p4 = *reinterpret_cast<const float4*>(prow + off);
    dot += v4.x * p4.x + v4.y * p4.y + v4.z * p4.z + v4.w * p4.w;
    vsq += v4.x * v4.x + v4.y * v4.y + v4.z * v4.z + v4.w * v4.w;
    psq += p4.x * p4.x + p4.y * p4.y + p4.z * p4.z + p4.w * p4.w;
  }
#pragma unroll
  for (int s = 1; s < 64; s <<= 1) {
    dot += __shfl_xor(dot, s);
    vsq += __shfl_xor(vsq, s);
    psq += __shfl_xor(psq, s);
  }
  if (lane == 0) {
    const float pn = fmaxf(sqrtf(psq), 1e-12f);
    const float vn = fmaxf(sqrtf(vsq), 1e-12f);
    sim[row] = dot / (pn * vn);
  }
}

__global__ __launch_bounds__(1024) void sinkhorn_kernel(
    const float* __restrict__ sim, float* __restrict__ gamma,
    float* __restrict__ mass_out) {
  const int b = blockIdx.x;
  const int t = threadIdx.x;
  __shared__ float red[16];
  const float* simb = sim + (size_t)b * kNP1;
  const float K0 = exp2f((simb[t] - 1.0f) * kSCALE);
  const float K1 = (t == 0) ? exp2f((simb[kN] - 1.0f) * kSCALE) : 0.0f;
  float v0 = 1.0f, v1 = 1.0f, u = 1.0f;
  for (int it = 0; it < 3; ++it) {
    float partial = K0 * v0 + K1 * v1;
#pragma unroll
    for (int s = 1; s < 64; s <<= 1) partial += __shfl_xor(partial, s);
    if ((t & 63) == 0) red[t >> 6] = partial;
    __syncthreads();
    float Kv = 0.f;
#pragma unroll
    for (int w = 0; w < 16; ++w) Kv += red[w];
    __syncthreads();
    u = exp2f(-kPOW * log2f(Kv + kEPS));
    v0 = exp2f(-kPOW * log2f(u * K0 + kEPS));
    v1 = exp2f(-kPOW * log2f(u * K1 + kEPS));
  }
  const float g0 = u * K0 * v0;
  gamma[(size_t)b * kN + t] = g0;
  float partial = g0;
#pragma unroll
  for (int s = 1; s < 64; s <<= 1) partial += __shfl_xor(partial, s);
  if ((t & 63) == 0) red[t >> 6] = partial;
  __syncthreads();
  if (t == 0) {
    float m = 0.f;
#pragma unroll
    for (int w = 0; w < 16; ++w) m += red[w];
    mass_out[b] = m;
  }
}

__global__ __launch_bounds__(512) void pobs_kernel(
    const float* __restrict__ vis, const float* __restrict__ gamma,
    float* __restrict__ partial) {
  const int b = blockIdx.x / kNSplit;
  const int s = blockIdx.x % kNSplit;
  const int c = threadIdx.x;
  __shared__ float gsm[kRowsPerSplit];
  const float* g = gamma + (size_t)b * kN + (size_t)s * kRowsPerSplit;
  for (int i = threadIdx.x; i < kRowsPerSplit; i += 512) gsm[i] = g[i];
  __syncthreads();
  const float* vbase = vis + ((size_t)b * kN + (size_t)s * kRowsPerSplit) * kC;
  float acc = 0.f;
#pragma unroll 8
  for (int n = 0; n < kRowsPerSplit; ++n)
    acc += gsm[n] * vbase[(size_t)n * kC + c];
  partial[(size_t)blockIdx.x * kC + c] = acc;
}

__global__ __launch_bounds__(256) void reduce_kernel(
    const float* __restrict__ partial, float* __restrict__ p_obs) {
  const int i = blockIdx.x * 256 + threadIdx.x;
  if (i >= kB * kC) return;
  const int b = i / kC;
  const int c = i % kC;
  float s = 0.f;
#pragma unroll
  for (int k = 0; k < kNSplit; ++k)
    s += partial[((size_t)(b * kNSplit + k)) * kC + c];
  p_obs[i] = s;
}

// ===========================================================================

extern "C" void kernel_launch(void* const* d_in, const int* in_sizes, int n_in,
                              void* d_out, int out_size, void* d_ws,
                              size_t ws_size, hipStream_t stream) {
  const float* prompt = (const float*)d_in[0];
  const float* vis = (const float*)d_in[1];
  const float* dustbin = (const float*)d_in[2];
  float* out = (float*)d_out;  // p_obs [B*C] then total_mass [B]

  if (ws_size >= kWsNeeded) {
    float* sim = (float*)d_ws;
    float* partials = (float*)((unsigned char*)d_ws + kPartOffB);
    sim_moment_kernel<<<kBlocks, 256, 0, stream>>>(prompt, vis, dustbin, sim,
                                                   partials);
    sinkhorn_combine_kernel<<<kB, 1024, 0, stream>>>(
        sim, partials, out, out + (size_t)kB * kC);
  } else {
    float* ws = (float*)d_ws;
    float* sim = ws + kFbSimOff;
    float* gamma = ws + kFbGammaOff;
    float* partial = ws + kFbPartialOff;
    const long long rows = (long long)kB * kNP1;
    sim_kernel<<<(int)((rows + 3) / 4), 256, 0, stream>>>(prompt, vis,
                                                          dustbin, sim);
    sinkhorn_kernel<<<kB, 1024, 0, stream>>>(sim, gamma, out + (size_t)kB * kC);
    pobs_kernel<<<kB * kNSplit, 512, 0, stream>>>(vis, gamma, partial);
    reduce_kernel<<<(kB * kC + 255) / 256, 256, 0, stream>>>(partial, out);
  }
}

// Round 13
// 110.784 us; speedup vs baseline: 1.0830x; 1.0270x over previous
//
#include <hip/hip_runtime.h>
#include <math.h>

namespace {
constexpr int kB = 256;
constexpr int kN = 1024;
constexpr int kC = 512;
constexpr int kNP1 = kN + 1;  // 1025 (visual rows + dustbin)
constexpr float kEPS = 1e-6f;
constexpr float kPOW = 0.9523809523809523f;    // ALPHA/(ALPHA+REG) = 1/1.05
constexpr float kSCALE = 28.8539008177792681f; // 20 * log2(e)

// series constants: gamma = u*K*(u*K+eps)^-POW, K = 2^-30 * Ks
//   p_obs = u*2^-30*eps^-POW * [M1 - POW*z*M2 + c2*z^2*M3 - c3*z^3*M4],
//   z = u * 2^-30/eps,  M_j = sum_n Ks_n^j * vis_nc
constexpr float kBaseC = 4.823755e-4f;   // 2^-30 * eps^-POW
constexpr float kZC = 9.3132257e-4f;     // 2^-30 / eps
constexpr float kC2 = 0.92970522f;       // POW(POW+1)/2
constexpr float kC3 = 0.91494840f;       // POW(POW+1)(POW+2)/6

constexpr int kChunksPerB = 4;             // round-10 geometry (proven best)
constexpr int kBlocks = kB * kChunksPerB;  // 1024

// ---- fast-path ws layout (bytes) ----
// sim      : [0, kB*kNP1*4)                      1,049,600 B
// partials : [+kBlocks * 4 moments * 512c * 4B)  8,388,608 B
constexpr size_t kSimBytes = (size_t)kB * kNP1 * sizeof(float);
constexpr size_t kPartOffB = kSimBytes;
constexpr size_t kWsNeeded =
    kSimBytes + (size_t)kBlocks * 4 * kC * sizeof(float);

// ---- fallback ws layout (floats) ----
constexpr size_t kFbSimOff = 0;
constexpr size_t kFbGammaOff = (size_t)kB * kNP1;
constexpr size_t kFbPartialOff = kFbGammaOff + (size_t)kB * kN;
constexpr int kNSplit = 4;
constexpr int kRowsPerSplit = kN / kNSplit;  // 256

typedef float f32x4 __attribute__((ext_vector_type(4)));
}  // namespace

// ===========================================================================
// K1: sims + 4 K-weighted moment partials, single pass over vis.
// 1024 blocks (4 per batch) x 256 threads (4 waves); wave owns 64 rows;
// lane owns channels [lane*8, lane*8+8). Moments accumulate in registers.
// (round-10 champion, verbatim)
// ===========================================================================
__global__ __launch_bounds__(256) void sim_moment_kernel(
    const float* __restrict__ prompt,    // [B, C]
    const float* __restrict__ vis,       // [B, N, C]
    const float* __restrict__ dustbin,   // [C]
    float* __restrict__ sim,             // [B, NP1] (ws)
    float* __restrict__ partials) {      // [kBlocks][4][512] (ws)
  const int w = threadIdx.x >> 6;        // wave 0..3
  const int lane = threadIdx.x & 63;
  const int b = blockIdx.x >> 2;
  const int chunk = blockIdx.x & 3;
  const int coff = lane * 8;

  __shared__ float lds[4][4][kC];  // 32 KB [wave][moment][channel]

  // prompt fragment + norm (once per wave)
  const float* prow = prompt + (size_t)b * kC;
  const f32x4 pa = *reinterpret_cast<const f32x4*>(prow + coff);
  const f32x4 pb = *reinterpret_cast<const f32x4*>(prow + coff + 4);
  float psq = pa.x * pa.x + pa.y * pa.y + pa.z * pa.z + pa.w * pa.w +
              pb.x * pb.x + pb.y * pb.y + pb.z * pb.z + pb.w * pb.w;
#pragma unroll
  for (int s = 1; s < 64; s <<= 1) psq += __shfl_xor(psq, s);
  const float pn = fmaxf(sqrtf(psq), 1e-12f);

  const int n0 = chunk * 256 + w * 64;   // first row of this wave
  const float* vbase = vis + ((size_t)b * kN + n0) * kC;
  float* simw = sim + (size_t)b * kNP1 + n0;

  float m1[8] = {0, 0, 0, 0, 0, 0, 0, 0};
  float m2[8] = {0, 0, 0, 0, 0, 0, 0, 0};
  float m3[8] = {0, 0, 0, 0, 0, 0, 0, 0};
  float m4[8] = {0, 0, 0, 0, 0, 0, 0, 0};

#pragma unroll 2
  for (int r = 0; r < 64; ++r) {
    const float* vrow = vbase + (size_t)r * kC;
    const f32x4 va = __builtin_nontemporal_load(
        reinterpret_cast<const f32x4*>(vrow + coff));
    const f32x4 vb = __builtin_nontemporal_load(
        reinterpret_cast<const f32x4*>(vrow + coff + 4));

    float dot = va.x * pa.x + va.y * pa.y + va.z * pa.z + va.w * pa.w +
                vb.x * pb.x + vb.y * pb.y + vb.z * pb.z + vb.w * pb.w;
    float vsq = va.x * va.x + va.y * va.y + va.z * va.z + va.w * va.w +
                vb.x * vb.x + vb.y * vb.y + vb.z * vb.z + vb.w * vb.w;
#pragma unroll
    for (int s = 1; s < 64; s <<= 1) {
      dot += __shfl_xor(dot, s);
      vsq += __shfl_xor(vsq, s);
    }
    const float sm = dot / (pn * fmaxf(sqrtf(vsq), 1e-12f));
    if (lane == 0) simw[r] = sm;

    // Ks = 2^30 * K = exp2(SCALE*(sim-1) + 30); range ~[0.03, 150]
    const float Ks = exp2f(kSCALE * (sm - 1.0f) + 30.0f);
    const float Ks2 = Ks * Ks;
    const float Ks3 = Ks2 * Ks;
    const float Ks4 = Ks2 * Ks2;
    m1[0] += Ks * va.x; m1[1] += Ks * va.y; m1[2] += Ks * va.z; m1[3] += Ks * va.w;
    m1[4] += Ks * vb.x; m1[5] += Ks * vb.y; m1[6] += Ks * vb.z; m1[7] += Ks * vb.w;
    m2[0] += Ks2 * va.x; m2[1] += Ks2 * va.y; m2[2] += Ks2 * va.z; m2[3] += Ks2 * va.w;
    m2[4] += Ks2 * vb.x; m2[5] += Ks2 * vb.y; m2[6] += Ks2 * vb.z; m2[7] += Ks2 * vb.w;
    m3[0] += Ks3 * va.x; m3[1] += Ks3 * va.y; m3[2] += Ks3 * va.z; m3[3] += Ks3 * va.w;
    m3[4] += Ks3 * vb.x; m3[5] += Ks3 * vb.y; m3[6] += Ks3 * vb.z; m3[7] += Ks3 * vb.w;
    m4[0] += Ks4 * va.x; m4[1] += Ks4 * va.y; m4[2] += Ks4 * va.z; m4[3] += Ks4 * va.w;
    m4[4] += Ks4 * vb.x; m4[5] += Ks4 * vb.y; m4[6] += Ks4 * vb.z; m4[7] += Ks4 * vb.w;
  }

  // dustbin sim (one wave per batch; excluded from moments/outputs)
  if (chunk == 3 && w == 3) {
    const f32x4 da = *reinterpret_cast<const f32x4*>(dustbin + coff);
    const f32x4 db = *reinterpret_cast<const f32x4*>(dustbin + coff + 4);
    float dot = da.x * pa.x + da.y * pa.y + da.z * pa.z + da.w * pa.w +
                db.x * pb.x + db.y * pb.y + db.z * pb.z + db.w * pb.w;
    float vsq = da.x * da.x + da.y * da.y + da.z * da.z + da.w * da.w +
                db.x * db.x + db.y * db.y + db.z * db.z + db.w * db.w;
#pragma unroll
    for (int s = 1; s < 64; s <<= 1) {
      dot += __shfl_xor(dot, s);
      vsq += __shfl_xor(vsq, s);
    }
    if (lane == 0)
      sim[(size_t)b * kNP1 + kN] = dot / (pn * fmaxf(sqrtf(vsq), 1e-12f));
  }

  // block-level moment reduce via LDS
#pragma unroll
  for (int j = 0; j < 8; ++j) {
    lds[w][0][coff + j] = m1[j];
    lds[w][1][coff + j] = m2[j];
    lds[w][2][coff + j] = m3[j];
    lds[w][3][coff + j] = m4[j];
  }
  __syncthreads();
#pragma unroll
  for (int h = 0; h < 2; ++h) {
    const int c = (int)threadIdx.x + h * 256;
#pragma unroll
    for (int m = 0; m < 4; ++m) {
      const float s =
          lds[0][m][c] + lds[1][m][c] + lds[2][m][c] + lds[3][m][c];
      partials[((size_t)blockIdx.x * 4 + m) * kC + c] = s;
    }
  }
}

// ===========================================================================
// K2': exact Sinkhorn from sims (unchanged math) -> u; exact total_mass;
// p_obs from the 4-moment series. One 1024-thread block per batch.
// ===========================================================================
__global__ __launch_bounds__(1024) void sinkhorn_combine_kernel(
    const float* __restrict__ sim,        // [B, NP1]
    const float* __restrict__ partials,   // [kBlocks][4][512]
    float* __restrict__ p_obs,            // [B, C]
    float* __restrict__ mass_out) {       // [B]
  const int b = blockIdx.x;
  const int t = threadIdx.x;
  __shared__ float red[16];

  const float* simb = sim + (size_t)b * kNP1;
  const float K0 = exp2f((simb[t] - 1.0f) * kSCALE);
  const float Kd = (t == 0) ? exp2f((simb[kN] - 1.0f) * kSCALE) : 0.0f;
  float v0 = 1.0f, vd = 1.0f, u = 1.0f;

#pragma unroll
  for (int it = 0; it < 3; ++it) {
    float partial = K0 * v0 + Kd * vd;
#pragma unroll
    for (int s = 1; s < 64; s <<= 1) partial += __shfl_xor(partial, s);
    if ((t & 63) == 0) red[t >> 6] = partial;
    __syncthreads();
    float Kv = 0.f;
#pragma unroll
    for (int w = 0; w < 16; ++w) Kv += red[w];
    __syncthreads();
    u = exp2f(-kPOW * log2f(Kv + kEPS));
    v0 = exp2f(-kPOW * log2f(u * K0 + kEPS));
    vd = exp2f(-kPOW * log2f(u * Kd + kEPS));
  }

  // exact gamma for n = t (< N always) -> total_mass
  const float g = u * K0 * v0;
  float pm = g;
#pragma unroll
  for (int s = 1; s < 64; s <<= 1) pm += __shfl_xor(pm, s);
  if ((t & 63) == 0) red[t >> 6] = pm;
  __syncthreads();
  if (t == 0) {
    float m = 0.f;
#pragma unroll
    for (int w = 0; w < 16; ++w) m += red[w];
    mass_out[b] = m;
  }

  // p_obs via moment series
  if (t < kC) {
    float M1 = 0.f, M2 = 0.f, M3 = 0.f, M4 = 0.f;
#pragma unroll
    for (int k = 0; k < kChunksPerB; ++k) {
      const size_t blk = (size_t)(b * kChunksPerB + k);
      M1 += partials[(blk * 4 + 0) * kC + t];
      M2 += partials[(blk * 4 + 1) * kC + t];
      M3 += partials[(blk * 4 + 2) * kC + t];
      M4 += partials[(blk * 4 + 3) * kC + t];
    }
    const float z = u * kZC;
    const float base = u * kBaseC;
    const float p =
        base * (M1 + z * (-kPOW * M2 + z * (kC2 * M3 - z * (kC3 * M4))));
    p_obs[(size_t)b * kC + t] = p;
  }
}

// ===========================================================================
// FALLBACK (fp32 two-pass, round-1 proven; used only if ws too small)
// ===========================================================================
__global__ __launch_bounds__(256) void sim_kernel(
    const float* __restrict__ prompt, const float* __restrict__ vis,
    const float* __restrict__ dustbin, float* __restrict__ sim) {
  const int wid = threadIdx.x >> 6;
  const int lane = threadIdx.x & 63;
  const long long row = (long long)blockIdx.x * 4 + wid;
  if (row >= (long long)kB * kNP1) return;
  const int b = (int)(row / kNP1);
  const int n = (int)(row % kNP1);
  const float* vrow = (n < kN) ? (vis + ((size_t)b * kN + n) * kC) : dustbin;
  const float* prow = prompt + (size_t)b * kC;
  float dot = 0.f, vsq = 0.f, psq = 0.f;
#pragma unroll
  for (int h = 0; h < 2; ++h) {
    const int off = h * 256 + lane * 4;
    const float4 v4 = *reinterpret_cast<const float4*>(vrow + off);
    const float4 p4 = *reinterpret_cast<const float4*>(prow + off);
    dot += v4.x * p4.x + v4.y * p4.y + v4.z * p4.z + v4.w * p4.w;
    vsq += v4.x * v4.x + v4.y * v4.y + v4.z * v4.z + v4.w * v4.w;
    psq += p4.x * p4.x + p4.y * p4.y + p4.z * p4.z + p4.w * p4.w;
  }
#pragma unroll
  for (int s = 1; s < 64; s <<= 1) {
    dot += __shfl_xor(dot, s);
    vsq += __shfl_xor(vsq, s);
    psq += __shfl_xor(psq, s);
  }
  if (lane == 0) {
    const float pn = fmaxf(sqrtf(psq), 1e-12f);
    const float vn = fmaxf(sqrtf(vsq), 1e-12f);
    sim[row] = dot / (pn * vn);
  }
}

__global__ __launch_bounds__(1024) void sinkhorn_kernel(
    const float* __restrict__ sim, float* __restrict__ gamma,
    float* __restrict__ mass_out) {
  const int b = blockIdx.x;
  const int t = threadIdx.x;
  __shared__ float red[16];
  const float* simb = sim + (size_t)b * kNP1;
  const float K0 = exp2f((simb[t] - 1.0f) * kSCALE);
  const float K1 = (t == 0) ? exp2f((simb[kN] - 1.0f) * kSCALE) : 0.0f;
  float v0 = 1.0f, v1 = 1.0f, u = 1.0f;
  for (int it = 0; it < 3; ++it) {
    float partial = K0 * v0 + K1 * v1;
#pragma unroll
    for (int s = 1; s < 64; s <<= 1) partial += __shfl_xor(partial, s);
    if ((t & 63) == 0) red[t >> 6] = partial;
    __syncthreads();
    float Kv = 0.f;
#pragma unroll
    for (int w = 0; w < 16; ++w) Kv += red[w];
    __syncthreads();
    u = exp2f(-kPOW * log2f(Kv + kEPS));
    v0 = exp2f(-kPOW * log2f(u * K0 + kEPS));
    v1 = exp2f(-kPOW * log2f(u * K1 + kEPS));
  }
  const float g0 = u * K0 * v0;
  gamma[(size_t)b * kN + t] = g0;
  float partial = g0;
#pragma unroll
  for (int s = 1; s < 64; s <<= 1) partial += __shfl_xor(partial, s);
  if ((t & 63) == 0) red[t >> 6] = partial;
  __syncthreads();
  if (t == 0) {
    float m = 0.f;
#pragma unroll
    for (int w = 0; w < 16; ++w) m += red[w];
    mass_out[b] = m;
  }
}

__global__ __launch_bounds__(512) void pobs_kernel(
    const float* __restrict__ vis, const float* __restrict__ gamma,
    float* __restrict__ partial) {
  const int b = blockIdx.x / kNSplit;
  const int s = blockIdx.x % kNSplit;
  const int c = threadIdx.x;
  __shared__ float gsm[kRowsPerSplit];
  const float* g = gamma + (size_t)b * kN + (size_t)s * kRowsPerSplit;
  for (int i = threadIdx.x; i < kRowsPerSplit; i += 512) gsm[i] = g[i];
  __syncthreads();
  const float* vbase = vis + ((size_t)b * kN + (size_t)s * kRowsPerSplit) * kC;
  float acc = 0.f;
#pragma unroll 8
  for (int n = 0; n < kRowsPerSplit; ++n)
    acc += gsm[n] * vbase[(size_t)n * kC + c];
  partial[(size_t)blockIdx.x * kC + c] = acc;
}

__global__ __launch_bounds__(256) void reduce_kernel(
    const float* __restrict__ partial, float* __restrict__ p_obs) {
  const int i = blockIdx.x * 256 + threadIdx.x;
  if (i >= kB * kC) return;
  const int b = i / kC;
  const int c = i % kC;
  float s = 0.f;
#pragma unroll
  for (int k = 0; k < kNSplit; ++k)
    s += partial[((size_t)(b * kNSplit + k)) * kC + c];
  p_obs[i] = s;
}

// ===========================================================================

extern "C" void kernel_launch(void* const* d_in, const int* in_sizes, int n_in,
                              void* d_out, int out_size, void* d_ws,
                              size_t ws_size, hipStream_t stream) {
  const float* prompt = (const float*)d_in[0];
  const float* vis = (const float*)d_in[1];
  const float* dustbin = (const float*)d_in[2];
  float* out = (float*)d_out;  // p_obs [B*C] then total_mass [B]

  if (ws_size >= kWsNeeded) {
    float* sim = (float*)d_ws;
    float* partials = (float*)((unsigned char*)d_ws + kPartOffB);
    sim_moment_kernel<<<kBlocks, 256, 0, stream>>>(prompt, vis, dustbin, sim,
                                                   partials);
    sinkhorn_combine_kernel<<<kB, 1024, 0, stream>>>(
        sim, partials, out, out + (size_t)kB * kC);
  } else {
    float* ws = (float*)d_ws;
    float* sim = ws + kFbSimOff;
    float* gamma = ws + kFbGammaOff;
    float* partial = ws + kFbPartialOff;
    const long long rows = (long long)kB * kNP1;
    sim_kernel<<<(int)((rows + 3) / 4), 256, 0, stream>>>(prompt, vis,
                                                          dustbin, sim);
    sinkhorn_kernel<<<kB, 1024, 0, stream>>>(sim, gamma, out + (size_t)kB * kC);
    pobs_kernel<<<kB * kNSplit, 512, 0, stream>>>(vis, gamma, partial);
    reduce_kernel<<<(kB * kC + 255) / 256, 256, 0, stream>>>(partial, out);
  }
}